// Round 1
// baseline (344.661 us; speedup 1.0000x reference)
//
#include <hip/hip_runtime.h>
#include <stdint.h>

typedef unsigned short u16;

#define B_ROWS 8192
#define IN_DIM 4096
#define MEM 256
#define D_IN 4352   // MEM + IN_DIM
#define N1 1024     // 512 | 256 | 256
#define K2 512
#define LN_EPS 1e-5f

typedef __attribute__((ext_vector_type(4))) float f32x4;
typedef __attribute__((ext_vector_type(4))) uint32_t u32x4;
typedef __attribute__((ext_vector_type(4))) unsigned short u16x4;
typedef __attribute__((ext_vector_type(8))) short bf16x8;  // 8 bf16 in 4 VGPRs

#define AS1(p) ((__attribute__((address_space(1))) void*)(p))
#define AS3(p) ((__attribute__((address_space(3))) void*)(p))

__device__ __forceinline__ float bf2f(u16 u) {
  union { uint32_t u; float f; } c; c.u = ((uint32_t)u) << 16; return c.f;
}
__device__ __forceinline__ u16 f2bf(float f) {  // round-to-nearest-even
  union { float f; uint32_t u; } c; c.f = f;
  uint32_t r = (c.u + 0x7fffu + ((c.u >> 16) & 1u)) >> 16;
  return (u16)r;
}
__device__ __forceinline__ uint32_t fbits(float f) {
  union { float f; uint32_t u; } c; c.f = f; return c.u;
}
__device__ __forceinline__ uint32_t pack_rne(float a, float b) {
  return ((uint32_t)f2bf(b) << 16) | f2bf(a);
}
__device__ __forceinline__ uint32_t pack_trunc(float a, float b) {
  return (fbits(b) & 0xFFFF0000u) | (fbits(a) >> 16);
}

// -------- merged prep: WT transpose (blocks 0..1087), W2F permute (1088..1103),
//          A cast (1104..18511) --------
__global__ __launch_bounds__(256)
void prep_kernel(const float* __restrict__ W1, const float* __restrict__ Wd,
                 const float* __restrict__ Wu, const float* __restrict__ W2,
                 const float* __restrict__ h, const float* __restrict__ x,
                 u16* __restrict__ WT, u16* __restrict__ W2F, u16* __restrict__ Abf) {
  __shared__ u16 tile[64][68];
  const int blk = blockIdx.x, t = threadIdx.x;
  if (blk < 1088) {
    // ---- {W1,Wd,Wu}[K][*] fp32 -> WT[1024][4352] bf16 (64x64 tiles) ----
    int n0 = (blk & 15) * 64, k0 = (blk >> 4) * 64;
    const float* src; int srcN, ns0;
    if (n0 < 512)      { src = W1; srcN = 512; ns0 = n0; }
    else if (n0 < 768) { src = Wd; srcN = 256; ns0 = n0 - 512; }
    else               { src = Wu; srcN = 256; ns0 = n0 - 768; }
    int rr = t >> 4;        // 0..15
    int c4 = (t & 15) * 4;  // 0..60
#pragma unroll
    for (int i = 0; i < 4; i++) {
      int k = i * 16 + rr;
      f32x4 v = *(const f32x4*)&src[(size_t)(k0 + k) * srcN + ns0 + c4];
      tile[c4 + 0][k] = f2bf(v[0]);
      tile[c4 + 1][k] = f2bf(v[1]);
      tile[c4 + 2][k] = f2bf(v[2]);
      tile[c4 + 3][k] = f2bf(v[3]);
    }
    __syncthreads();
#pragma unroll
    for (int i = 0; i < 4; i++) {
      int n = i * 16 + rr;
      u16x4 w;
      w.x = tile[n][c4 + 0];
      w.y = tile[n][c4 + 1];
      w.z = tile[n][c4 + 2];
      w.w = tile[n][c4 + 3];
      *(u16x4*)&WT[(size_t)(n0 + n) * D_IN + k0 + c4] = w;
    }
  } else if (blk < 1104) {
    // ---- W2[512][256] fp32 -> W2F fragment-major bf16:
    //      W2F[((kw*4+q)*256 + n)*8 + j] = bf16(W2[kw*32+q*8+j][n]) ----
    int kw = blk - 1088;
#pragma unroll
    for (int q = 0; q < 4; q++) {
      float v[8];
#pragma unroll
      for (int j = 0; j < 8; j++)
        v[j] = W2[(size_t)(kw * 32 + q * 8 + j) * 256 + t];
      u32x4 w;
      w.x = pack_rne(v[0], v[1]);
      w.y = pack_rne(v[2], v[3]);
      w.z = pack_rne(v[4], v[5]);
      w.w = pack_rne(v[6], v[7]);
      *(u32x4*)&W2F[(size_t)((kw * 4 + q) * 256 + t) * 8] = w;
    }
  } else {
    // ---- [h|x] fp32 -> Abf bf16 [8192][4352], 8 elems/thread ----
    int b = blk - 1104;
    const float* src; int r, dcol;
    if (b < 1024) {
      int g = (b * 256 + t) * 8;
      src = h + g; r = g >> 8; dcol = g & 255;
    } else {
      int g = ((b - 1024) * 256 + t) * 8;
      src = x + g; r = g >> 12; dcol = MEM + (g & 4095);
    }
    f32x4 v0 = *(const f32x4*)src;
    f32x4 v1 = *(const f32x4*)(src + 4);
    u32x4 w;
    w.x = pack_rne(v0[0], v0[1]);
    w.y = pack_rne(v0[2], v0[3]);
    w.z = pack_rne(v1[0], v1[1]);
    w.w = pack_rne(v1[2], v1[3]);
    *(u32x4*)&Abf[(size_t)r * D_IN + dcol] = w;
  }
}

// ============================================================================
// GEMM1, 256x256-tile 8-phase schedule (T2+T3+T4+T5), split-K=2.
//   grid 256 blocks x 512 threads (8 waves, 2M x 4N), 1 block/CU.
//   LDS 128 KB: A,B double-buffered, layout [buf][khalf][row][4 granules of 16B]
//   with granule swizzle g ^= (row>>1)&3 (2-way bank conflicts = free).
//   Per K-tile (BK=64): 4 phases = (khalf x mhalf) quadrants, 16 MFMA each.
//   Each phase stages one half (2 x global_load_lds w=16) of the NEXT K-tile
//   into the other buffer. Waits: s_waitcnt vmcnt(4) twice per tile (counted,
//   never drained in the main loop). Per-wave in-flight invariant at each
//   tile boundary: 4 loads (= next tile's k1 halves).
// ============================================================================
#define BAR() { asm volatile("" ::: "memory"); __builtin_amdgcn_s_barrier(); asm volatile("" ::: "memory"); }
#define VMW4() asm volatile("s_waitcnt vmcnt(4)" ::: "memory");
#define VMW0() asm volatile("s_waitcnt vmcnt(0)" ::: "memory");

__global__ __launch_bounds__(512, 2)
void gemm1_pre256_kernel(const u16* __restrict__ Abf, const u16* __restrict__ WT,
                         u16* __restrict__ G0, u16* __restrict__ G1, int klen) {
  __shared__ __attribute__((aligned(16))) u16 As[2][16384];  // 2 x 32 KB
  __shared__ __attribute__((aligned(16))) u16 Bs[2][16384];  // 2 x 32 KB
  const int t = threadIdx.x;
  const int lane = t & 63, wave = t >> 6;
  // XCD-chunked swizzle (bijective: 256 % 8 == 0). Each XCD's 32 blocks share
  // one (part, bx) B-panel (1.1 MB) in its private L2.
  const int bid = (int)blockIdx.x;
  const int swz = (bid & 7) * 32 + (bid >> 3);
  const int by = swz & 31;        // M tile [0,32)
  const int bx = (swz >> 5) & 3;  // N tile [0,4)
  const int part = swz >> 7;      // K part [0,2)
  const int kbase = part * klen;
  u16* __restrict__ Gout = part ? G1 : G0;
  const int row0 = by * 256, col0 = bx * 256;
  const int q = lane >> 4, mrow = lane & 15;
  const int wm = wave >> 2, wn = wave & 3;
  const int NT = klen >> 6;

  // Staging decomposition: one k-half of one operand = 1024 granules (16B),
  // 2 insts x 512 threads. Linear LDS dest granule idx = j*512+t -> (row=idx>>2,
  // g=idx&3); global source granule column = g ^ ((row>>1)&3)  (inverse swizzle).
  int sr0, sc0_, sr1, sc1_;
  {
    int idx0 = t;        sr0 = idx0 >> 2; sc0_ = (idx0 & 3) ^ ((sr0 >> 1) & 3);
    int idx1 = 512 + t;  sr1 = idx1 >> 2; sc1_ = (idx1 & 3) ^ ((sr1 >> 1) & 3);
  }
  const u16* pa0 = Abf + (size_t)(row0 + sr0) * D_IN + sc0_ * 8;
  const u16* pa1 = Abf + (size_t)(row0 + sr1) * D_IN + sc1_ * 8;
  const u16* pb0 = WT  + (size_t)(col0 + sr0) * D_IN + sc0_ * 8;
  const u16* pb1 = WT  + (size_t)(col0 + sr1) * D_IN + sc1_ * 8;
  const int fsw = (mrow >> 1) & 3;  // fragment read swizzle (row>>1)&3

#define STAGE_A(buf, kk, kt)                                                            \
  __builtin_amdgcn_global_load_lds(AS1(pa0 + (kt) + (kk) * 32),                         \
      AS3(&As[buf][(kk) * 8192 + t * 8]), 16, 0, 0);                                    \
  __builtin_amdgcn_global_load_lds(AS1(pa1 + (kt) + (kk) * 32),                         \
      AS3(&As[buf][(kk) * 8192 + (512 + t) * 8]), 16, 0, 0);
#define STAGE_B(buf, kk, kt)                                                            \
  __builtin_amdgcn_global_load_lds(AS1(pb0 + (kt) + (kk) * 32),                         \
      AS3(&Bs[buf][(kk) * 8192 + t * 8]), 16, 0, 0);                                    \
  __builtin_amdgcn_global_load_lds(AS1(pb1 + (kt) + (kk) * 32),                         \
      AS3(&Bs[buf][(kk) * 8192 + (512 + t) * 8]), 16, 0, 0);

  f32x4 acc[8][4] = {};

  // ---- prologue: stage tile 0 fully into buf 0; wait for its k-half0 ----
  STAGE_A(0, 0, kbase)
  STAGE_B(0, 0, kbase)
  STAGE_A(0, 1, kbase)
  STAGE_B(0, 1, kbase)
  VMW4();
  BAR();

  for (int tt = 0; tt < NT; ++tt) {
    const int cur = tt & 1, nxt = cur ^ 1;
    const int kn = kbase + (tt + 1) * 64;
    const bool pf = (tt + 1 < NT);
    bf16x8 a[4], b[4];

#define READ_B(kk)                                                                      \
  _Pragma("unroll") for (int nt = 0; nt < 4; nt++) {                                    \
    int crow = wn * 64 + nt * 16 + mrow;                                                \
    b[nt] = *(const bf16x8*)&Bs[cur][(kk) * 8192 + crow * 32 + (q ^ fsw) * 8];          \
  }
#define READ_A(kk, mh)                                                                  \
  _Pragma("unroll") for (int i = 0; i < 4; i++) {                                       \
    int arow = wm * 128 + ((mh) * 4 + i) * 16 + mrow;                                   \
    a[i] = *(const bf16x8*)&As[cur][(kk) * 8192 + arow * 32 + (q ^ fsw) * 8];           \
  }
#define MFMA16(mh)                                                                      \
  __builtin_amdgcn_s_setprio(1);                                                        \
  _Pragma("unroll") for (int i = 0; i < 4; i++)                                         \
    _Pragma("unroll") for (int nt = 0; nt < 4; nt++)                                    \
      acc[(mh) * 4 + i][nt] =                                                           \
          __builtin_amdgcn_mfma_f32_16x16x32_bf16(a[i], b[nt], acc[(mh) * 4 + i][nt], 0, 0, 0); \
  __builtin_amdgcn_s_setprio(0);

    // ---- phase 1: (k0, m0); stage next A-k0 ----
    READ_B(0)
    READ_A(0, 0)
    if (pf) { STAGE_A(nxt, 0, kn) }
    BAR();
    MFMA16(0)
    BAR();
    // ---- phase 2: (k0, m1); stage next B-k0; wait: this tile's k1 landed ----
    READ_A(0, 1)
    if (pf) { STAGE_B(nxt, 0, kn) }
    BAR();
    MFMA16(1)
    if (pf) { VMW4(); } else { VMW0(); }
    BAR();
    // ---- phase 3: (k1, m0); stage next A-k1 ----
    READ_B(1)
    READ_A(1, 0)
    if (pf) { STAGE_A(nxt, 1, kn) }
    BAR();
    MFMA16(0)
    BAR();
    // ---- phase 4: (k1, m1); stage next B-k1; wait: next tile's k0 landed ----
    READ_A(1, 1)
    if (pf) { STAGE_B(nxt, 1, kn) }
    BAR();
    MFMA16(1)
    if (pf) { VMW4(); }
    BAR();
#undef READ_B
#undef READ_A
#undef MFMA16
  }

  // ---- epilogue: C write (16x16 C layout: col=lane&15, row=(lane>>4)*4+reg) ----
#pragma unroll
  for (int mt = 0; mt < 8; mt++) {
#pragma unroll
    for (int nt = 0; nt < 4; nt++) {
#pragma unroll
      for (int i = 0; i < 4; i++) {
        int row = row0 + wm * 128 + mt * 16 + q * 4 + i;
        int col = col0 + wn * 64 + nt * 16 + mrow;
        Gout[(size_t)row * N1 + col] = f2bf(acc[mt][nt][i]);
      }
    }
  }
}
#undef STAGE_A
#undef STAGE_B

// -------- fallback GEMM1 (inline fp32->bf16 A staging, 128x128 m97) --------
__global__ __launch_bounds__(256, 4)
void gemm1_inline_kernel(const float* __restrict__ x, const float* __restrict__ h,
                         const u16* __restrict__ WT, u16* __restrict__ G0,
                         u16* __restrict__ G1, int klen) {
  __shared__ __attribute__((aligned(16))) u16 As[128 * 64];
  __shared__ __attribute__((aligned(16))) u16 Bs[128 * 64];
  const int t = threadIdx.x;
  const int lane = t & 63, wave = t >> 6;
  const int by = blockIdx.x & 63;
  const int bx = (blockIdx.x >> 6) & 7;
  const int part = blockIdx.x >> 9;
  const int kbase = part * klen;
  u16* __restrict__ Gout = part ? G1 : G0;
  const int row0 = by * 128, col0 = bx * 128;
  const int q = lane >> 4, mrow = lane & 15;
  const int wm = wave >> 1, wn = wave & 1;

  int ar[4], ac[4];
#pragma unroll
  for (int j = 0; j < 4; j++) {
    int idx = j * 256 + t;
    int r = idx >> 3;
    ar[j] = r;
    ac[j] = (idx & 7) ^ (r & 7);
  }
  f32x4 acc[4][4] = {};
  for (int k0 = kbase; k0 < kbase + klen; k0 += 64) {
#pragma unroll
    for (int j = 0; j < 4; j++) {
      const u16* gp = WT + (size_t)(col0 + ar[j]) * D_IN + k0 + ac[j] * 8;
      __builtin_amdgcn_global_load_lds(AS1(gp), AS3(&Bs[(j * 256 + t) * 8]), 16, 0, 0);
    }
#pragma unroll
    for (int j = 0; j < 4; j++) {
      int k = k0 + ac[j] * 8;
      const float* gp = (k < MEM) ? (h + (size_t)(row0 + ar[j]) * MEM + k)
                                  : (x + (size_t)(row0 + ar[j]) * IN_DIM + (k - MEM));
      f32x4 v0 = *(const f32x4*)gp;
      f32x4 v1 = *(const f32x4*)(gp + 4);
      u32x4 w;
      w.x = pack_trunc(v0[0], v0[1]);
      w.y = pack_trunc(v0[2], v0[3]);
      w.z = pack_trunc(v1[0], v1[1]);
      w.w = pack_trunc(v1[2], v1[3]);
      *(u32x4*)&As[(j * 256 + t) * 8] = w;
    }
    __syncthreads();
#pragma unroll
    for (int kk = 0; kk < 2; kk++) {
      bf16x8 a[4], b[4];
#pragma unroll
      for (int mt = 0; mt < 4; mt++) {
        int row = wm * 64 + mt * 16 + mrow;
        int p = (kk * 4 + q) ^ (mrow & 7);
        a[mt] = *(const bf16x8*)&As[row * 64 + p * 8];
      }
#pragma unroll
      for (int nt = 0; nt < 4; nt++) {
        int row = wn * 64 + nt * 16 + mrow;
        int p = (kk * 4 + q) ^ (mrow & 7);
        b[nt] = *(const bf16x8*)&Bs[row * 64 + p * 8];
      }
#pragma unroll
      for (int mt = 0; mt < 4; mt++) {
#pragma unroll
        for (int nt = 0; nt < 4; nt++) {
          acc[mt][nt] = __builtin_amdgcn_mfma_f32_16x16x32_bf16(a[mt], b[nt], acc[mt][nt], 0, 0, 0);
        }
      }
    }
    __syncthreads();
  }
#pragma unroll
  for (int mt = 0; mt < 4; mt++) {
#pragma unroll
    for (int nt = 0; nt < 4; nt++) {
#pragma unroll
      for (int i = 0; i < 4; i++) {
        int row = row0 + wm * 64 + mt * 16 + q * 4 + i;
        int col = col0 + wn * 64 + nt * 16 + mrow;
        Gout[(size_t)row * N1 + col] = f2bf(acc[mt][nt][i]);
      }
    }
  }
}

// -------- fused LN+GELU+GEMM2+epilogue -> out fp32 [8192][256] --------
__global__ __launch_bounds__(256, 4)
void fused_ln_gemm2_kernel(const u16* __restrict__ G0, const u16* __restrict__ G1,
                           const u16* __restrict__ W2F, const float* __restrict__ h,
                           const float* __restrict__ b1v, const float* __restrict__ g1v,
                           const float* __restrict__ be1v, const float* __restrict__ b2,
                           const float* __restrict__ bd, const float* __restrict__ bu,
                           float* __restrict__ out, int nparts) {
  __shared__ __attribute__((aligned(16))) u16 As[16 * 512];   // 16 KB
  __shared__ float redA[16][4], redB[16][4], scl[16];
  const int t = threadIdx.x, lane = t & 63, wave = t >> 6;
  const int q = lane >> 4, mrow = lane & 15;
  const int r0 = blockIdx.x * 16;

  // ---- Phase 1: LN + exact GELU ----
  {
    const int lr = t & 15;   // row in tile
    const int lc = t >> 4;   // 32-col chunk [0,16)
    float z[32];
    const u16* g0p = G0 + (size_t)(r0 + lr) * N1 + lc * 32;
    const u16* g1p = G1 + (size_t)(r0 + lr) * N1 + lc * 32;
    float s = 0.f, ss = 0.f;
#pragma unroll
    for (int j = 0; j < 4; j++) {
      u32x4 w0 = *(const u32x4*)(g0p + j * 8);
      u32x4 w1;
      if (nparts == 2) w1 = *(const u32x4*)(g1p + j * 8);
#pragma unroll
      for (int e = 0; e < 4; e++) {
        float lo = bf2f((u16)(w0[e] & 0xffff));
        float hi = bf2f((u16)(w0[e] >> 16));
        if (nparts == 2) {
          lo += bf2f((u16)(w1[e] & 0xffff));
          hi += bf2f((u16)(w1[e] >> 16));
        }
        int cb = lc * 32 + j * 8 + e * 2;
        lo += b1v[cb];
        hi += b1v[cb + 1];
        z[j * 8 + e * 2] = lo;
        z[j * 8 + e * 2 + 1] = hi;
        s += lo + hi;
        ss += lo * lo + hi * hi;
      }
    }
    s += __shfl_xor(s, 16, 64);  s += __shfl_xor(s, 32, 64);
    ss += __shfl_xor(ss, 16, 64); ss += __shfl_xor(ss, 32, 64);
    if (lane < 16) { redA[lr][wave] = s; redB[lr][wave] = ss; }
    __syncthreads();
    float S  = redA[lr][0] + redA[lr][1] + redA[lr][2] + redA[lr][3];
    float SS = redB[lr][0] + redB[lr][1] + redB[lr][2] + redB[lr][3];
    float mu = S * (1.0f / 512.0f);
    float var = SS * (1.0f / 512.0f) - mu * mu;
    float rstd = rsqrtf(var + LN_EPS);
#pragma unroll
    for (int j = 0; j < 4; j++) {
      u32x4 wpk;
#pragma unroll
      for (int e = 0; e < 4; e++) {
        int cb = lc * 32 + j * 8 + e * 2;
        float y0 = (z[j * 8 + e * 2] - mu) * rstd * g1v[cb] + be1v[cb];
        float y1 = (z[j * 8 + e * 2 + 1] - mu) * rstd * g1v[cb + 1] + be1v[cb + 1];
        float o0 = 0.5f * y0 * (1.0f + erff(y0 * 0.7071067811865475f));
        float o1 = 0.5f * y1 * (1.0f + erff(y1 * 0.7071067811865475f));
        wpk[e] = pack_rne(o0, o1);
      }
      int p = lc * 4 + j;            // chunk index [0,64)
      int ps = p ^ (lr & 7);
      *(u32x4*)&As[lr * 512 + ps * 8] = wpk;
    }
  }
  __syncthreads();  // As visible to all waves

  // ---- Phase 2: barrier-free GEMM. B streams global->VGPR from W2F (L2-hot) ----
  f32x4 acc[4] = {};
#pragma unroll
  for (int kw = 0; kw < 16; kw++) {
    int pa = (kw * 4 + q) ^ (mrow & 7);
    bf16x8 a = *(const bf16x8*)&As[mrow * 512 + pa * 8];
#pragma unroll
    for (int nt = 0; nt < 4; nt++) {
      const u16* bp = W2F + (size_t)((kw * 4 + q) * 256 + wave * 64 + nt * 16 + mrow) * 8;
      bf16x8 b = *(const bf16x8*)bp;
      acc[nt] = __builtin_amdgcn_mfma_f32_16x16x32_bf16(a, b, acc[nt], 0, 0, 0);
    }
  }
  __syncthreads();  // before redA/redB reuse

  // ---- Phase 3: gates + blend + row-norm rescale ----
  float snh[4], shh[4];
#pragma unroll
  for (int i = 0; i < 4; i++) {
    int r = q * 4 + i;
    size_t grow = (size_t)(r0 + r);
    float a_nh = 0.f, a_h = 0.f;
#pragma unroll
    for (int nt = 0; nt < 4; nt++) {
      int c = wave * 64 + nt * 16 + mrow;
      float hc = tanhf(acc[nt][i] + b2[c]);
      float zd = bf2f(G0[grow * N1 + 512 + c]);
      float zu = bf2f(G0[grow * N1 + 768 + c]);
      if (nparts == 2) {
        zd += bf2f(G1[grow * N1 + 512 + c]);
        zu += bf2f(G1[grow * N1 + 768 + c]);
      }
      zd += bd[c];
      zu += bu[c];
      float dec = 0.1f + 9.9f / (1.0f + expf(-zd)) + 1e-6f;
      float u = 1.0f / (1.0f + expf(-zu));
      float hv = h[grow * MEM + c];
      float nh = (1.0f - u) * (hv / dec) + u * hc;
      acc[nt][i] = nh;
      a_nh += nh * nh;
      a_h += hv * hv;
    }
    snh[i] = a_nh;
    shh[i] = a_h;
  }
#pragma unroll
  for (int m = 1; m <= 8; m <<= 1) {
#pragma unroll
    for (int i = 0; i < 4; i++) {
      snh[i] += __shfl_xor(snh[i], m, 64);
      shh[i] += __shfl_xor(shh[i], m, 64);
    }
  }
  if (mrow == 0) {
#pragma unroll
    for (int i = 0; i < 4; i++) {
      int r = q * 4 + i;
      redA[r][wave] = snh[i];
      redB[r][wave] = shh[i];
    }
  }
  __syncthreads();
  if (t < 16) {
    float tn = redA[t][0] + redA[t][1] + redA[t][2] + redA[t][3];
    float th = redB[t][0] + redB[t][1] + redB[t][2] + redB[t][3];
    float hn = fmaxf(sqrtf(th), 1e-6f);
    float nn = fmaxf(sqrtf(tn), 1e-12f);
    scl[t] = hn / nn;
  }
  __syncthreads();
#pragma unroll
  for (int i = 0; i < 4; i++) {
    int r = q * 4 + i;
    size_t grow = (size_t)(r0 + r);
    float sc = scl[r];
#pragma unroll
    for (int nt = 0; nt < 4; nt++) {
      int c = wave * 64 + nt * 16 + mrow;
      out[grow * MEM + c] = acc[nt][i] * sc;
    }
  }
}

extern "C" void kernel_launch(void* const* d_in, const int* in_sizes, int n_in,
                              void* d_out, int out_size, void* d_ws, size_t ws_size,
                              hipStream_t stream) {
  const float* x   = (const float*)d_in[0];
  const float* h   = (const float*)d_in[1];
  const float* W1  = (const float*)d_in[2];
  const float* b1  = (const float*)d_in[3];
  const float* g1  = (const float*)d_in[4];
  const float* be1 = (const float*)d_in[5];
  const float* W2  = (const float*)d_in[6];
  const float* b2  = (const float*)d_in[7];
  const float* Wd  = (const float*)d_in[8];
  const float* bd  = (const float*)d_in[9];
  const float* Wu  = (const float*)d_in[10];
  const float* bu  = (const float*)d_in[11];
  float* out = (float*)d_out;

  // workspace: WT 8,912,896 | W2F 262,144 | G0 16,777,216 | G1 16,777,216 | Abf 71,303,168
  char* ws = (char*)d_ws;
  u16* WT  = (u16*)(ws);
  u16* W2F = (u16*)(ws + 8912896);
  u16* G0  = (u16*)(ws + 9175040);
  u16* G1  = (u16*)(ws + 25952256);
  u16* Abf = (u16*)(ws + 42729472);

  const int nparts = (ws_size >= 42729472u) ? 2 : 1;
  const int klen = D_IN / nparts;
  const bool use_pre = (ws_size >= 114032640u) && (nparts == 2);

  if (use_pre) {
    prep_kernel<<<18512, 256, 0, stream>>>(W1, Wd, Wu, W2, h, x, WT, W2F, Abf);
    gemm1_pre256_kernel<<<256, 512, 0, stream>>>(Abf, WT, G0, G1, klen);
  } else {
    prep_kernel<<<1104, 256, 0, stream>>>(W1, Wd, Wu, W2, h, x, WT, W2F, Abf);
    gemm1_inline_kernel<<<512 * nparts, 256, 0, stream>>>(x, h, WT, G0, G1, klen);
  }

  fused_ln_gemm2_kernel<<<B_ROWS / 16, 256, 0, stream>>>(G0, G1, W2F, h, b1, g1, be1,
                                                         b2, bd, bu, out, nparts);
}

// Round 2
// 338.073 us; speedup vs baseline: 1.0195x; 1.0195x over previous
//
#include <hip/hip_runtime.h>
#include <stdint.h>

typedef unsigned short u16;

#define B_ROWS 8192
#define IN_DIM 4096
#define MEM 256
#define D_IN 4352   // MEM + IN_DIM
#define N1 1024     // 512 | 256 | 256
#define K2 512
#define LN_EPS 1e-5f

typedef __attribute__((ext_vector_type(4))) float f32x4;
typedef __attribute__((ext_vector_type(4))) uint32_t u32x4;
typedef __attribute__((ext_vector_type(4))) unsigned short u16x4;
typedef __attribute__((ext_vector_type(8))) short bf16x8;  // 8 bf16 in 4 VGPRs

#define AS1(p) ((__attribute__((address_space(1))) void*)(p))
#define AS3(p) ((__attribute__((address_space(3))) void*)(p))

__device__ __forceinline__ float bf2f(u16 u) {
  union { uint32_t u; float f; } c; c.u = ((uint32_t)u) << 16; return c.f;
}
__device__ __forceinline__ u16 f2bf(float f) {  // round-to-nearest-even
  union { float f; uint32_t u; } c; c.f = f;
  uint32_t r = (c.u + 0x7fffu + ((c.u >> 16) & 1u)) >> 16;
  return (u16)r;
}
__device__ __forceinline__ uint32_t fbits(float f) {
  union { float f; uint32_t u; } c; c.f = f; return c.u;
}
__device__ __forceinline__ uint32_t pack_rne(float a, float b) {
  return ((uint32_t)f2bf(b) << 16) | f2bf(a);
}
__device__ __forceinline__ uint32_t pack_trunc(float a, float b) {
  return (fbits(b) & 0xFFFF0000u) | (fbits(a) >> 16);
}

// -------- merged prep: WT transpose (blocks 0..1087), W2F permute (1088..1103),
//          A cast (1104..18511) --------
__global__ __launch_bounds__(256)
void prep_kernel(const float* __restrict__ W1, const float* __restrict__ Wd,
                 const float* __restrict__ Wu, const float* __restrict__ W2,
                 const float* __restrict__ h, const float* __restrict__ x,
                 u16* __restrict__ WT, u16* __restrict__ W2F, u16* __restrict__ Abf) {
  __shared__ u16 tile[64][68];
  const int blk = blockIdx.x, t = threadIdx.x;
  if (blk < 1088) {
    // ---- {W1,Wd,Wu}[K][*] fp32 -> WT[1024][4352] bf16 (64x64 tiles) ----
    int n0 = (blk & 15) * 64, k0 = (blk >> 4) * 64;
    const float* src; int srcN, ns0;
    if (n0 < 512)      { src = W1; srcN = 512; ns0 = n0; }
    else if (n0 < 768) { src = Wd; srcN = 256; ns0 = n0 - 512; }
    else               { src = Wu; srcN = 256; ns0 = n0 - 768; }
    int rr = t >> 4;        // 0..15
    int c4 = (t & 15) * 4;  // 0..60
#pragma unroll
    for (int i = 0; i < 4; i++) {
      int k = i * 16 + rr;
      f32x4 v = *(const f32x4*)&src[(size_t)(k0 + k) * srcN + ns0 + c4];
      tile[c4 + 0][k] = f2bf(v[0]);
      tile[c4 + 1][k] = f2bf(v[1]);
      tile[c4 + 2][k] = f2bf(v[2]);
      tile[c4 + 3][k] = f2bf(v[3]);
    }
    __syncthreads();
#pragma unroll
    for (int i = 0; i < 4; i++) {
      int n = i * 16 + rr;
      u16x4 w;
      w.x = tile[n][c4 + 0];
      w.y = tile[n][c4 + 1];
      w.z = tile[n][c4 + 2];
      w.w = tile[n][c4 + 3];
      *(u16x4*)&WT[(size_t)(n0 + n) * D_IN + k0 + c4] = w;
    }
  } else if (blk < 1104) {
    // ---- W2[512][256] fp32 -> W2F fragment-major bf16:
    //      W2F[((kw*4+q)*256 + n)*8 + j] = bf16(W2[kw*32+q*8+j][n]) ----
    int kw = blk - 1088;
#pragma unroll
    for (int q = 0; q < 4; q++) {
      float v[8];
#pragma unroll
      for (int j = 0; j < 8; j++)
        v[j] = W2[(size_t)(kw * 32 + q * 8 + j) * 256 + t];
      u32x4 w;
      w.x = pack_rne(v[0], v[1]);
      w.y = pack_rne(v[2], v[3]);
      w.z = pack_rne(v[4], v[5]);
      w.w = pack_rne(v[6], v[7]);
      *(u32x4*)&W2F[(size_t)((kw * 4 + q) * 256 + t) * 8] = w;
    }
  } else {
    // ---- [h|x] fp32 -> Abf bf16 [8192][4352], 8 elems/thread ----
    int b = blk - 1104;
    const float* src; int r, dcol;
    if (b < 1024) {
      int g = (b * 256 + t) * 8;
      src = h + g; r = g >> 8; dcol = g & 255;
    } else {
      int g = ((b - 1024) * 256 + t) * 8;
      src = x + g; r = g >> 12; dcol = MEM + (g & 4095);
    }
    f32x4 v0 = *(const f32x4*)src;
    f32x4 v1 = *(const f32x4*)(src + 4);
    u32x4 w;
    w.x = pack_rne(v0[0], v0[1]);
    w.y = pack_rne(v0[2], v0[3]);
    w.z = pack_rne(v1[0], v1[1]);
    w.w = pack_rne(v1[2], v1[3]);
    *(u32x4*)&Abf[(size_t)r * D_IN + dcol] = w;
  }
}

// ============================================================================
// GEMM1, 256x256-tile 8-phase schedule (T2+T3+T4+T5), split-K=2.
//   grid 256 blocks x 512 threads (8 waves, 2M x 4N), 1 block/CU.
//   XCD-2D swizzle: XCD x owns {part = x>>2, by in [(x&3)*8, +8), all 4 bx}.
//   Within an XCD: each A panel shared by 4 blocks, each B panel by 8 ->
//   per-K-tile L2-external traffic 384 KB/XCD (vs 1056 KB with 1-D chunking),
//   and A is fetched from HBM exactly once chip-wide.
//   LDS 128 KB: A,B double-buffered, [buf][khalf][row][4 granules of 16B],
//   granule swizzle g ^= (row>>1)&3 (2-way conflicts = free).
//   Per K-tile (BK=64): 4 phases = (khalf x mhalf), 16 MFMA each; each phase
//   stages one half of the NEXT tile; counted s_waitcnt vmcnt(4) twice/tile.
// ============================================================================
#define BAR() { asm volatile("" ::: "memory"); __builtin_amdgcn_s_barrier(); asm volatile("" ::: "memory"); }
#define VMW4() asm volatile("s_waitcnt vmcnt(4)" ::: "memory");
#define VMW0() asm volatile("s_waitcnt vmcnt(0)" ::: "memory");

__global__ __launch_bounds__(512, 2)
void gemm1_pre256_kernel(const u16* __restrict__ Abf, const u16* __restrict__ WT,
                         u16* __restrict__ G0, u16* __restrict__ G1, int klen) {
  __shared__ __attribute__((aligned(16))) u16 As[2][16384];  // 2 x 32 KB
  __shared__ __attribute__((aligned(16))) u16 Bs[2][16384];  // 2 x 32 KB
  const int t = threadIdx.x;
  const int lane = t & 63, wave = t >> 6;
  // ---- XCD-2D block swizzle (bijective over 256 = 8 XCD x 32) ----
  const int bid = (int)blockIdx.x;
  const int xcd = bid & 7;                   // hardware XCD (round-robin dispatch)
  const int idx = bid >> 3;                  // [0,32) position within XCD
  const int part = xcd >> 2;                 // XCDs 0-3: K-part 0; 4-7: part 1
  const int by = (xcd & 3) * 8 + (idx & 7);  // [0,32): 8 M-panels per XCD
  const int bx = idx >> 3;                   // [0,4):  all N-panels per XCD
  const int kbase = part * klen;
  u16* __restrict__ Gout = part ? G1 : G0;
  const int row0 = by * 256, col0 = bx * 256;
  const int q = lane >> 4, mrow = lane & 15;
  const int wm = wave >> 2, wn = wave & 3;
  const int NT = klen >> 6;

  // Staging decomposition: one k-half of one operand = 1024 granules (16B),
  // 2 insts x 512 threads. Linear LDS dest granule idx = j*512+t -> (row=idx>>2,
  // g=idx&3); global source granule column = g ^ ((row>>1)&3)  (inverse swizzle).
  int sr0, sc0_, sr1, sc1_;
  {
    int idx0 = t;        sr0 = idx0 >> 2; sc0_ = (idx0 & 3) ^ ((sr0 >> 1) & 3);
    int idx1 = 512 + t;  sr1 = idx1 >> 2; sc1_ = (idx1 & 3) ^ ((sr1 >> 1) & 3);
  }
  const u16* pa0 = Abf + (size_t)(row0 + sr0) * D_IN + sc0_ * 8;
  const u16* pa1 = Abf + (size_t)(row0 + sr1) * D_IN + sc1_ * 8;
  const u16* pb0 = WT  + (size_t)(col0 + sr0) * D_IN + sc0_ * 8;
  const u16* pb1 = WT  + (size_t)(col0 + sr1) * D_IN + sc1_ * 8;
  const int fsw = (mrow >> 1) & 3;  // fragment read swizzle (row>>1)&3

#define STAGE_A(buf, kk, kt)                                                            \
  __builtin_amdgcn_global_load_lds(AS1(pa0 + (kt) + (kk) * 32),                         \
      AS3(&As[buf][(kk) * 8192 + t * 8]), 16, 0, 0);                                    \
  __builtin_amdgcn_global_load_lds(AS1(pa1 + (kt) + (kk) * 32),                         \
      AS3(&As[buf][(kk) * 8192 + (512 + t) * 8]), 16, 0, 0);
#define STAGE_B(buf, kk, kt)                                                            \
  __builtin_amdgcn_global_load_lds(AS1(pb0 + (kt) + (kk) * 32),                         \
      AS3(&Bs[buf][(kk) * 8192 + t * 8]), 16, 0, 0);                                    \
  __builtin_amdgcn_global_load_lds(AS1(pb1 + (kt) + (kk) * 32),                         \
      AS3(&Bs[buf][(kk) * 8192 + (512 + t) * 8]), 16, 0, 0);

  f32x4 acc[8][4] = {};

  // ---- prologue: stage tile 0 fully into buf 0; wait for its k-half0 ----
  STAGE_A(0, 0, kbase)
  STAGE_B(0, 0, kbase)
  STAGE_A(0, 1, kbase)
  STAGE_B(0, 1, kbase)
  VMW4();
  BAR();

  for (int tt = 0; tt < NT; ++tt) {
    const int cur = tt & 1, nxt = cur ^ 1;
    const int kn = kbase + (tt + 1) * 64;
    const bool pf = (tt + 1 < NT);
    bf16x8 a[4], b[4];

#define READ_B(kk)                                                                      \
  _Pragma("unroll") for (int nt = 0; nt < 4; nt++) {                                    \
    int crow = wn * 64 + nt * 16 + mrow;                                                \
    b[nt] = *(const bf16x8*)&Bs[cur][(kk) * 8192 + crow * 32 + (q ^ fsw) * 8];          \
  }
#define READ_A(kk, mh)                                                                  \
  _Pragma("unroll") for (int i = 0; i < 4; i++) {                                       \
    int arow = wm * 128 + ((mh) * 4 + i) * 16 + mrow;                                   \
    a[i] = *(const bf16x8*)&As[cur][(kk) * 8192 + arow * 32 + (q ^ fsw) * 8];           \
  }
#define MFMA16(mh)                                                                      \
  __builtin_amdgcn_s_setprio(1);                                                        \
  _Pragma("unroll") for (int i = 0; i < 4; i++)                                         \
    _Pragma("unroll") for (int nt = 0; nt < 4; nt++)                                    \
      acc[(mh) * 4 + i][nt] =                                                           \
          __builtin_amdgcn_mfma_f32_16x16x32_bf16(a[i], b[nt], acc[(mh) * 4 + i][nt], 0, 0, 0); \
  __builtin_amdgcn_s_setprio(0);

    // ---- phase 1: (k0, m0); stage next A-k0 ----
    READ_B(0)
    READ_A(0, 0)
    if (pf) { STAGE_A(nxt, 0, kn) }
    BAR();
    MFMA16(0)
    BAR();
    // ---- phase 2: (k0, m1); stage next B-k0; wait: this tile's k1 landed ----
    READ_A(0, 1)
    if (pf) { STAGE_B(nxt, 0, kn) }
    BAR();
    MFMA16(1)
    if (pf) { VMW4(); } else { VMW0(); }
    BAR();
    // ---- phase 3: (k1, m0); stage next A-k1 ----
    READ_B(1)
    READ_A(1, 0)
    if (pf) { STAGE_A(nxt, 1, kn) }
    BAR();
    MFMA16(0)
    BAR();
    // ---- phase 4: (k1, m1); stage next B-k1; wait: next tile's k0 landed ----
    READ_A(1, 1)
    if (pf) { STAGE_B(nxt, 1, kn) }
    BAR();
    MFMA16(1)
    if (pf) { VMW4(); }
    BAR();
#undef READ_B
#undef READ_A
#undef MFMA16
  }

  // ---- epilogue: C write (16x16 C layout: col=lane&15, row=(lane>>4)*4+reg) ----
#pragma unroll
  for (int mt = 0; mt < 8; mt++) {
#pragma unroll
    for (int nt = 0; nt < 4; nt++) {
#pragma unroll
      for (int i = 0; i < 4; i++) {
        int row = row0 + wm * 128 + mt * 16 + q * 4 + i;
        int col = col0 + wn * 64 + nt * 16 + mrow;
        Gout[(size_t)row * N1 + col] = f2bf(acc[mt][nt][i]);
      }
    }
  }
}
#undef STAGE_A
#undef STAGE_B

// -------- fallback GEMM1 (inline fp32->bf16 A staging, 128x128 m97) --------
__global__ __launch_bounds__(256, 4)
void gemm1_inline_kernel(const float* __restrict__ x, const float* __restrict__ h,
                         const u16* __restrict__ WT, u16* __restrict__ G0,
                         u16* __restrict__ G1, int klen) {
  __shared__ __attribute__((aligned(16))) u16 As[128 * 64];
  __shared__ __attribute__((aligned(16))) u16 Bs[128 * 64];
  const int t = threadIdx.x;
  const int lane = t & 63, wave = t >> 6;
  const int by = blockIdx.x & 63;
  const int bx = (blockIdx.x >> 6) & 7;
  const int part = blockIdx.x >> 9;
  const int kbase = part * klen;
  u16* __restrict__ Gout = part ? G1 : G0;
  const int row0 = by * 128, col0 = bx * 128;
  const int q = lane >> 4, mrow = lane & 15;
  const int wm = wave >> 1, wn = wave & 1;

  int ar[4], ac[4];
#pragma unroll
  for (int j = 0; j < 4; j++) {
    int idx = j * 256 + t;
    int r = idx >> 3;
    ar[j] = r;
    ac[j] = (idx & 7) ^ (r & 7);
  }
  f32x4 acc[4][4] = {};
  for (int k0 = kbase; k0 < kbase + klen; k0 += 64) {
#pragma unroll
    for (int j = 0; j < 4; j++) {
      const u16* gp = WT + (size_t)(col0 + ar[j]) * D_IN + k0 + ac[j] * 8;
      __builtin_amdgcn_global_load_lds(AS1(gp), AS3(&Bs[(j * 256 + t) * 8]), 16, 0, 0);
    }
#pragma unroll
    for (int j = 0; j < 4; j++) {
      int k = k0 + ac[j] * 8;
      const float* gp = (k < MEM) ? (h + (size_t)(row0 + ar[j]) * MEM + k)
                                  : (x + (size_t)(row0 + ar[j]) * IN_DIM + (k - MEM));
      f32x4 v0 = *(const f32x4*)gp;
      f32x4 v1 = *(const f32x4*)(gp + 4);
      u32x4 w;
      w.x = pack_trunc(v0[0], v0[1]);
      w.y = pack_trunc(v0[2], v0[3]);
      w.z = pack_trunc(v1[0], v1[1]);
      w.w = pack_trunc(v1[2], v1[3]);
      *(u32x4*)&As[(j * 256 + t) * 8] = w;
    }
    __syncthreads();
#pragma unroll
    for (int kk = 0; kk < 2; kk++) {
      bf16x8 a[4], b[4];
#pragma unroll
      for (int mt = 0; mt < 4; mt++) {
        int row = wm * 64 + mt * 16 + mrow;
        int p = (kk * 4 + q) ^ (mrow & 7);
        a[mt] = *(const bf16x8*)&As[row * 64 + p * 8];
      }
#pragma unroll
      for (int nt = 0; nt < 4; nt++) {
        int row = wn * 64 + nt * 16 + mrow;
        int p = (kk * 4 + q) ^ (mrow & 7);
        b[nt] = *(const bf16x8*)&Bs[row * 64 + p * 8];
      }
#pragma unroll
      for (int mt = 0; mt < 4; mt++) {
#pragma unroll
        for (int nt = 0; nt < 4; nt++) {
          acc[mt][nt] = __builtin_amdgcn_mfma_f32_16x16x32_bf16(a[mt], b[nt], acc[mt][nt], 0, 0, 0);
        }
      }
    }
    __syncthreads();
  }
#pragma unroll
  for (int mt = 0; mt < 4; mt++) {
#pragma unroll
    for (int nt = 0; nt < 4; nt++) {
#pragma unroll
      for (int i = 0; i < 4; i++) {
        int row = row0 + wm * 64 + mt * 16 + q * 4 + i;
        int col = col0 + wn * 64 + nt * 16 + mrow;
        Gout[(size_t)row * N1 + col] = f2bf(acc[mt][nt][i]);
      }
    }
  }
}

// -------- fused LN+GELU+GEMM2+epilogue -> out fp32 [8192][256] --------
__global__ __launch_bounds__(256, 4)
void fused_ln_gemm2_kernel(const u16* __restrict__ G0, const u16* __restrict__ G1,
                           const u16* __restrict__ W2F, const float* __restrict__ h,
                           const float* __restrict__ b1v, const float* __restrict__ g1v,
                           const float* __restrict__ be1v, const float* __restrict__ b2,
                           const float* __restrict__ bd, const float* __restrict__ bu,
                           float* __restrict__ out, int nparts) {
  __shared__ __attribute__((aligned(16))) u16 As[16 * 512];   // 16 KB
  __shared__ float redA[16][4], redB[16][4], scl[16];
  const int t = threadIdx.x, lane = t & 63, wave = t >> 6;
  const int q = lane >> 4, mrow = lane & 15;
  const int r0 = blockIdx.x * 16;

  // ---- Phase 1: LN + exact GELU ----
  {
    const int lr = t & 15;   // row in tile
    const int lc = t >> 4;   // 32-col chunk [0,16)
    float z[32];
    const u16* g0p = G0 + (size_t)(r0 + lr) * N1 + lc * 32;
    const u16* g1p = G1 + (size_t)(r0 + lr) * N1 + lc * 32;
    float s = 0.f, ss = 0.f;
#pragma unroll
    for (int j = 0; j < 4; j++) {
      u32x4 w0 = *(const u32x4*)(g0p + j * 8);
      u32x4 w1;
      if (nparts == 2) w1 = *(const u32x4*)(g1p + j * 8);
#pragma unroll
      for (int e = 0; e < 4; e++) {
        float lo = bf2f((u16)(w0[e] & 0xffff));
        float hi = bf2f((u16)(w0[e] >> 16));
        if (nparts == 2) {
          lo += bf2f((u16)(w1[e] & 0xffff));
          hi += bf2f((u16)(w1[e] >> 16));
        }
        int cb = lc * 32 + j * 8 + e * 2;
        lo += b1v[cb];
        hi += b1v[cb + 1];
        z[j * 8 + e * 2] = lo;
        z[j * 8 + e * 2 + 1] = hi;
        s += lo + hi;
        ss += lo * lo + hi * hi;
      }
    }
    s += __shfl_xor(s, 16, 64);  s += __shfl_xor(s, 32, 64);
    ss += __shfl_xor(ss, 16, 64); ss += __shfl_xor(ss, 32, 64);
    if (lane < 16) { redA[lr][wave] = s; redB[lr][wave] = ss; }
    __syncthreads();
    float S  = redA[lr][0] + redA[lr][1] + redA[lr][2] + redA[lr][3];
    float SS = redB[lr][0] + redB[lr][1] + redB[lr][2] + redB[lr][3];
    float mu = S * (1.0f / 512.0f);
    float var = SS * (1.0f / 512.0f) - mu * mu;
    float rstd = rsqrtf(var + LN_EPS);
#pragma unroll
    for (int j = 0; j < 4; j++) {
      u32x4 wpk;
#pragma unroll
      for (int e = 0; e < 4; e++) {
        int cb = lc * 32 + j * 8 + e * 2;
        float y0 = (z[j * 8 + e * 2] - mu) * rstd * g1v[cb] + be1v[cb];
        float y1 = (z[j * 8 + e * 2 + 1] - mu) * rstd * g1v[cb + 1] + be1v[cb + 1];
        float o0 = 0.5f * y0 * (1.0f + erff(y0 * 0.7071067811865475f));
        float o1 = 0.5f * y1 * (1.0f + erff(y1 * 0.7071067811865475f));
        wpk[e] = pack_rne(o0, o1);
      }
      int p = lc * 4 + j;            // chunk index [0,64)
      int ps = p ^ (lr & 7);
      *(u32x4*)&As[lr * 512 + ps * 8] = wpk;
    }
  }
  __syncthreads();  // As visible to all waves

  // ---- Phase 2: barrier-free GEMM. B streams global->VGPR from W2F (L2-hot) ----
  f32x4 acc[4] = {};
#pragma unroll
  for (int kw = 0; kw < 16; kw++) {
    int pa = (kw * 4 + q) ^ (mrow & 7);
    bf16x8 a = *(const bf16x8*)&As[mrow * 512 + pa * 8];
#pragma unroll
    for (int nt = 0; nt < 4; nt++) {
      const u16* bp = W2F + (size_t)((kw * 4 + q) * 256 + wave * 64 + nt * 16 + mrow) * 8;
      bf16x8 b = *(const bf16x8*)bp;
      acc[nt] = __builtin_amdgcn_mfma_f32_16x16x32_bf16(a, b, acc[nt], 0, 0, 0);
    }
  }
  __syncthreads();  // before redA/redB reuse

  // ---- Phase 3: gates + blend + row-norm rescale ----
  float snh[4], shh[4];
#pragma unroll
  for (int i = 0; i < 4; i++) {
    int r = q * 4 + i;
    size_t grow = (size_t)(r0 + r);
    float a_nh = 0.f, a_h = 0.f;
#pragma unroll
    for (int nt = 0; nt < 4; nt++) {
      int c = wave * 64 + nt * 16 + mrow;
      float hc = tanhf(acc[nt][i] + b2[c]);
      float zd = bf2f(G0[grow * N1 + 512 + c]);
      float zu = bf2f(G0[grow * N1 + 768 + c]);
      if (nparts == 2) {
        zd += bf2f(G1[grow * N1 + 512 + c]);
        zu += bf2f(G1[grow * N1 + 768 + c]);
      }
      zd += bd[c];
      zu += bu[c];
      float dec = 0.1f + 9.9f / (1.0f + expf(-zd)) + 1e-6f;
      float u = 1.0f / (1.0f + expf(-zu));
      float hv = h[grow * MEM + c];
      float nh = (1.0f - u) * (hv / dec) + u * hc;
      acc[nt][i] = nh;
      a_nh += nh * nh;
      a_h += hv * hv;
    }
    snh[i] = a_nh;
    shh[i] = a_h;
  }
#pragma unroll
  for (int m = 1; m <= 8; m <<= 1) {
#pragma unroll
    for (int i = 0; i < 4; i++) {
      snh[i] += __shfl_xor(snh[i], m, 64);
      shh[i] += __shfl_xor(shh[i], m, 64);
    }
  }
  if (mrow == 0) {
#pragma unroll
    for (int i = 0; i < 4; i++) {
      int r = q * 4 + i;
      redA[r][wave] = snh[i];
      redB[r][wave] = shh[i];
    }
  }
  __syncthreads();
  if (t < 16) {
    float tn = redA[t][0] + redA[t][1] + redA[t][2] + redA[t][3];
    float th = redB[t][0] + redB[t][1] + redB[t][2] + redB[t][3];
    float hn = fmaxf(sqrtf(th), 1e-6f);
    float nn = fmaxf(sqrtf(tn), 1e-12f);
    scl[t] = hn / nn;
  }
  __syncthreads();
#pragma unroll
  for (int i = 0; i < 4; i++) {
    int r = q * 4 + i;
    size_t grow = (size_t)(r0 + r);
    float sc = scl[r];
#pragma unroll
    for (int nt = 0; nt < 4; nt++) {
      int c = wave * 64 + nt * 16 + mrow;
      out[grow * MEM + c] = acc[nt][i] * sc;
    }
  }
}

extern "C" void kernel_launch(void* const* d_in, const int* in_sizes, int n_in,
                              void* d_out, int out_size, void* d_ws, size_t ws_size,
                              hipStream_t stream) {
  const float* x   = (const float*)d_in[0];
  const float* h   = (const float*)d_in[1];
  const float* W1  = (const float*)d_in[2];
  const float* b1  = (const float*)d_in[3];
  const float* g1  = (const float*)d_in[4];
  const float* be1 = (const float*)d_in[5];
  const float* W2  = (const float*)d_in[6];
  const float* b2  = (const float*)d_in[7];
  const float* Wd  = (const float*)d_in[8];
  const float* bd  = (const float*)d_in[9];
  const float* Wu  = (const float*)d_in[10];
  const float* bu  = (const float*)d_in[11];
  float* out = (float*)d_out;

  // workspace: WT 8,912,896 | W2F 262,144 | G0 16,777,216 | G1 16,777,216 | Abf 71,303,168
  char* ws = (char*)d_ws;
  u16* WT  = (u16*)(ws);
  u16* W2F = (u16*)(ws + 8912896);
  u16* G0  = (u16*)(ws + 9175040);
  u16* G1  = (u16*)(ws + 25952256);
  u16* Abf = (u16*)(ws + 42729472);

  const int nparts = (ws_size >= 42729472u) ? 2 : 1;
  const int klen = D_IN / nparts;
  const bool use_pre = (ws_size >= 114032640u) && (nparts == 2);

  if (use_pre) {
    prep_kernel<<<18512, 256, 0, stream>>>(W1, Wd, Wu, W2, h, x, WT, W2F, Abf);
    gemm1_pre256_kernel<<<256, 512, 0, stream>>>(Abf, WT, G0, G1, klen);
  } else {
    prep_kernel<<<1104, 256, 0, stream>>>(W1, Wd, Wu, W2, h, x, WT, W2F, Abf);
    gemm1_inline_kernel<<<512 * nparts, 256, 0, stream>>>(x, h, WT, G0, G1, klen);
  }

  fused_ln_gemm2_kernel<<<B_ROWS / 16, 256, 0, stream>>>(G0, G1, W2F, h, b1, g1, be1,
                                                         b2, bd, bu, out, nparts);
}